// Round 19
// baseline (3677.691 us; speedup 1.0000x reference)
//
#include <hip/hip_runtime.h>
#include <hip/hip_fp16.h>

typedef _Float16 f16;
typedef _Float16 f16x8 __attribute__((ext_vector_type(8)));
typedef float f32x4 __attribute__((ext_vector_type(4)));

#define TT 512

// ws layout (bytes)
#define XH_OFF    0                 // x as f16: 512*64*256*2 = 16777216
#define WP_OFF    16777216          // packed weights f16: 7340032
#define HA_OFF    24117248          // h_a hub ring: 4 x 65536
#define HB_OFF    24379392          // h_b hub double buffer: 2 x 65536
#define BAR_OFF   24510464          // 64 slot ints + 2 gen ints
#define WS_NEED   24510976

#define WP_L1_HOFF 1572864          // half-offset of layer1 slice in wpack
#define LDS_BYTES 131072            // weights only

// counted vmcnt wait + scheduler fence (guide rule #18)
#define WAITV(N) do { \
    asm volatile("s_waitcnt vmcnt(" #N ")" ::: "memory"); \
    __builtin_amdgcn_sched_barrier(0); \
  } while (0)

// ---------------- prep kernels ----------------

__global__ void k_pack_w(const float* __restrict__ W0, const float* __restrict__ U0,
                         const float* __restrict__ W1, const float* __restrict__ U1,
                         f16* __restrict__ wp) {
  int idx = blockIdx.x * 256 + threadIdx.x;
  if (idx >= 458752) return;
  if (idx < 196608) {              // layer0: [w][ct][s=24][lane]
    int w = idx / 6144, r = idx % 6144;
    int ct = r / 1536, r2 = r % 1536;
    int s = r2 / 64, lane = r2 % 64;
    int g = ct * 512 + w * 16 + (lane & 15);
    int kb = s * 32 + (lane >> 4) * 8;
    f16* dst = wp + (size_t)idx * 8;
#pragma unroll
    for (int j = 0; j < 8; ++j) {
      int k = kb + j;
      float v = (k < 256) ? W0[g * 256 + k] : U0[g * 512 + (k - 256)];
      dst[j] = (f16)v;
    }
  } else {                         // layer1: [w][ct][s=32][lane]
    int i2 = idx - 196608;
    int w = i2 / 8192, r = i2 % 8192;
    int ct = r / 2048, r2 = r % 2048;
    int s = r2 / 64, lane = r2 % 64;
    int g = ct * 512 + w * 16 + (lane & 15);
    int kb = s * 32 + (lane >> 4) * 8;
    f16* dst = wp + (size_t)WP_L1_HOFF + (size_t)i2 * 8;
#pragma unroll
    for (int j = 0; j < 8; ++j) {
      int k = kb + j;
      float v = (k < 512) ? W1[g * 512 + k] : U1[g * 512 + (k - 512)];
      dst[j] = (f16)v;
    }
  }
}

__global__ void k_pack_x(const float* __restrict__ x, f16* __restrict__ xh) {
  int t = blockIdx.x * 256 + threadIdx.x;
  if (t >= 1048576) return;
  const float4* s = (const float4*)(x) + (size_t)t * 2;
  float4 a = s[0], b = s[1];
  f16x8 o;
  o[0] = (f16)a.x; o[1] = (f16)a.y; o[2] = (f16)a.z; o[3] = (f16)a.w;
  o[4] = (f16)b.x; o[5] = (f16)b.y; o[6] = (f16)b.z; o[7] = (f16)b.w;
  *(f16x8*)(xh + (size_t)t * 8) = o;
}

__global__ void k_init(const float* __restrict__ h0, f16* __restrict__ ha,
                       f16* __restrict__ hb, int* __restrict__ slots) {
  int i = blockIdx.x * 256 + threadIdx.x;
  if (i < 32768) {
    ha[i] = (f16)h0[i];                    // h_a ring[0] <- h0[0]
  } else if (i < 65536) {
    hb[i] = (f16)h0[i];                    // h_b buf1 <- h0[1]
  }
  if (i < 66) slots[i] = 0;                // 64 slots + 2 gen words
}

// ---------------- math helpers ----------------

__device__ __forceinline__ float sigmoidf_(float x) {
  return 1.0f / (1.0f + __expf(-x));
}
__device__ __forceinline__ float tanhf_(float x) {
  x = fminf(fmaxf(x, -15.0f), 15.0f);
  float e = __expf(-2.0f * x);
  return (1.0f - e) / (1.0f + e);
}

// device-coherent (MALL) 16B load: bypasses stale L1/L2 (validated path)
__device__ __forceinline__ uint4 ldg_coh(const void* base, unsigned voff) {
  uint4 d;
  asm volatile("global_load_dwordx4 %0, %1, %2 sc0 sc1"
               : "=v"(d) : "v"(voff), "s"(base) : "memory");
  return d;
}
// normal cached 16B load (read-only x)
__device__ __forceinline__ uint4 ldg_x(const void* base, unsigned voff) {
  uint4 d;
  asm volatile("global_load_dwordx4 %0, %1, %2"
               : "=v"(d) : "v"(voff), "s"(base) : "memory");
  return d;
}

// ---------------- persistent LSTM ----------------

template <int LAYER>
__device__ void lstm_body(const f16* __restrict__ xh, const f16* __restrict__ wp,
                          f16* __restrict__ ha, f16* __restrict__ hb,
                          int* __restrict__ slots, const float* __restrict__ c0,
                          const float* __restrict__ bb, float* __restrict__ dout,
                          f16* lds) {
  constexpr int NX = (LAYER == 0) ? 8 : 0;    // x K-steps (K=32 each)
  constexpr int NH = (LAYER == 0) ? 16 : 32;  // h K-steps
  constexpr int NK = NX + NH;                 // LDS B layout stride
  const int wg = blockIdx.x;
  const int w = wg & 31;
  const int tid = threadIdx.x, lane = tid & 63, wv = tid >> 6;
  int* gens = slots + 64;                     // gens[0]=layer0, gens[1]=layer1

  // copy this WG's weight slice into LDS (once; reused all phases)
  {
    const uint4* src = (const uint4*)(wp + (LAYER ? (size_t)WP_L1_HOFF + (size_t)w * 65536
                                                  : (size_t)w * 49152));
    uint4* dst = (uint4*)lds;
    const int n16 = LAYER ? 8192 : 6144;    // halfs/8
    for (int i = tid; i < n16; i += 256) dst[i] = src[i];
  }

  const int j15 = lane & 15;
  const int l4 = lane >> 4;
  const int hidb = w * 16 + j15;
  const float bi = bb[hidb], bf = bb[512 + hidb], bo = bb[1024 + hidb], bc = bb[1536 + hidb];

  float cr[4];
#pragma unroll
  for (int r = 0; r < 4; ++r) {
    int n = 16 * wv + l4 * 4 + r;
    cr[r] = c0[(size_t)LAYER * 32768 + n * 512 + hidb];
  }

  // per-lane byte offsets: each wave owns rows 16*wv .. 16*wv+15 (no redundancy)
  const int row = 16 * wv + j15;
  const unsigned hoffs = (unsigned)(row * 1024 + l4 * 16);
  const unsigned xoffs = (unsigned)(row * 512 + l4 * 16);

  uint4 ax[(LAYER == 0) ? 8 : 1];
  uint4 ah[NH];

  auto issue_x = [&](int pp) {
    if constexpr (LAYER == 0) {
      const char* xb = (const char*)xh + (size_t)pp * 32768;
#pragma unroll
      for (int s = 0; s < 8; ++s) ax[s] = ldg_x(xb, xoffs + s * 64);
    }
  };

  __syncthreads();                           // weights staged
  issue_x(0);

  bool broken = false;
  for (int p = 0; p <= TT; ++p) {
    const char* hard = (const char*)ha + (size_t)(p & 3) * 65536;   // ring slot
    const char* hbrd = (const char*)hb + (size_t)(p & 1) * 65536;
    f16* hwr = (LAYER == 0) ? (ha + ((p + 1) & 3) * 32768)
                            : (hb + (((p & 1) ^ 1) * 32768));
    const bool active = (LAYER == 0) ? (p < TT) : (p >= 1);

    f32x4 acc[4];
#pragma unroll
    for (int ct = 0; ct < 4; ++ct) acc[ct] = (f32x4){0.f, 0.f, 0.f, 0.f};

    auto mstep = [&](uint4 Au, int sB) {
      f16x8 a = __builtin_bit_cast(f16x8, Au);
#pragma unroll
      for (int ct = 0; ct < 4; ++ct) {
        f16x8 b = *(const f16x8*)(lds + (((ct * NK + sB) * 64 + lane) * 8));
        acc[ct] = __builtin_amdgcn_mfma_f32_16x16x32_f16(a, b, acc[ct], 0, 0, 0);
      }
    };

    if constexpr (LAYER == 0) {
      // --- L0: x-part first (regs only), acquire overlapped mid-body ---
      if (active) {
        WAITV(0);                             // x[p] in regs (p=0: prologue loads)
#pragma unroll
        for (int s = 0; s < 8; ++s) mstep(ax[s], s);
      }
      // mid-body acquire (runs for all p, incl p==TT final gen0 publish):
      // leader: slots>=p -> gen0=p -> ring wait gen1>=p-2; members poll gens.
      {
        const int needG1 = p - 2;
        if (wv == 0 && !broken) {
          if (w == 0) {
            const int* gs = slots;
            unsigned spins = 0;
            for (;;) {
              int v = __hip_atomic_load(gs + (lane & 31), __ATOMIC_RELAXED,
                                        __HIP_MEMORY_SCOPE_AGENT);
              if (__all((int)(v >= p))) break;
              __builtin_amdgcn_s_sleep(1);
              if (++spins > (1u << 20)) { broken = true; break; }
            }
            __hip_atomic_store(gens + 0, p, __ATOMIC_RELAXED,
                               __HIP_MEMORY_SCOPE_AGENT);
            if (needG1 > 0 && !broken) {
              unsigned s2 = 0;
              while (__hip_atomic_load(gens + 1, __ATOMIC_RELAXED,
                                       __HIP_MEMORY_SCOPE_AGENT) < needG1) {
                __builtin_amdgcn_s_sleep(2);
                if (++s2 > (1u << 20)) { broken = true; break; }
              }
            }
          } else {
            unsigned spins = 0;
            for (;;) {
              unsigned long long g = __hip_atomic_load((const unsigned long long*)gens,
                                                       __ATOMIC_RELAXED,
                                                       __HIP_MEMORY_SCOPE_AGENT);
              int g0 = (int)(unsigned)g, g1 = (int)(unsigned)(g >> 32);
              if (g0 >= p && g1 >= needG1) break;
              __builtin_amdgcn_s_sleep(2);
              if (++spins > (1u << 20)) { broken = true; break; }
            }
          }
        }
      }
      __builtin_amdgcn_s_barrier();           // h_a[p] readable; ring safe

      if (active) {
        if (p + 1 < TT) issue_x(p + 1);       // 8 loads (oldest; retire under h RTT)
#pragma unroll
        for (int t = 0; t < 16; ++t) ah[t] = ldg_coh(hard, hoffs + t * 64);
        WAITV(8);                             // x[p+1] + h[0..7] done
#pragma unroll
        for (int t = 0; t < 8; ++t) mstep(ah[t], 8 + t);
        WAITV(0);                             // h[8..15] done
#pragma unroll
        for (int t = 8; t < 16; ++t) mstep(ah[t], 8 + t);
      }
    } else if (active) {
      // --- L1: byte-identical to r18 (h_a first; gen1 handshake mid-phase) ---
#pragma unroll
      for (int t = 0; t < 16; ++t) ah[t] = ldg_coh(hard, hoffs + t * 64);
      WAITV(8);                               // h_a[0..7]
#pragma unroll
      for (int t = 0; t < 8; ++t) mstep(ah[t], t);

      if (wv == 0 && !broken) {
        if (w == 0) {                         // L1 group leader (wg 32)
          const int* gs = slots + 32;
          unsigned spins = 0;
          for (;;) {
            int v = __hip_atomic_load(gs + (lane & 31), __ATOMIC_RELAXED,
                                      __HIP_MEMORY_SCOPE_AGENT);
            if (__all((int)(v >= p))) break;
            __builtin_amdgcn_s_sleep(1);
            if (++spins > (1u << 20)) { broken = true; break; }
          }
          __hip_atomic_store(gens + 1, p, __ATOMIC_RELAXED,
                             __HIP_MEMORY_SCOPE_AGENT);
        } else {
          unsigned spins = 0;
          while (__hip_atomic_load(gens + 1, __ATOMIC_RELAXED,
                                   __HIP_MEMORY_SCOPE_AGENT) < p) {
            __builtin_amdgcn_s_sleep(1);
            if (++spins > (1u << 20)) { broken = true; break; }
          }
        }
      }
      __builtin_amdgcn_s_barrier();           // h_b[p] readable

#pragma unroll
      for (int t = 16; t < 32; ++t) ah[t] = ldg_coh(hbrd, hoffs + (t - 16) * 64);
      WAITV(16);                              // h_a[8..15] (hides h_b RTT)
#pragma unroll
      for (int t = 8; t < 16; ++t) mstep(ah[t], t);
      WAITV(8);                               // h_b[0..7]
#pragma unroll
      for (int t = 16; t < 24; ++t) mstep(ah[t], t);
      WAITV(0);                               // h_b[8..15]
#pragma unroll
      for (int t = 24; t < 32; ++t) mstep(ah[t], t);
    }

    if (active) {
      // epilogue straight from registers: acc[ct][r] = gate ct, row 16wv+l4*4+r
      const bool last = (p == (LAYER ? TT : TT - 1));
#pragma unroll
      for (int r = 0; r < 4; ++r) {
        int n = 16 * wv + l4 * 4 + r;
        float gi = acc[0][r] + bi;
        float gf = acc[1][r] + bf;
        float go = acc[2][r] + bo;
        float gc = acc[3][r] + bc;
        float ig = sigmoidf_(gi), fg = sigmoidf_(gf), og = sigmoidf_(go);
        float cg = tanhf_(gc);
        float c = fg * cr[r] + ig * cg;
        cr[r] = c;
        float h = og * tanhf_(c);
        // pack (even,odd) hid pair across lane pair; write-through coherent store
        unsigned short us = __builtin_bit_cast(unsigned short, (f16)h);
        unsigned other = __shfl_xor((unsigned)us, 1, 64);
        if (!(lane & 1)) {
          unsigned pack = (unsigned)us | (other << 16);
          __hip_atomic_store((unsigned*)(hwr + n * 512 + hidb), pack,
                             __ATOMIC_RELAXED, __HIP_MEMORY_SCOPE_AGENT);
        }
        if (last) {
          dout[8192 + LAYER * 32768 + n * 512 + hidb] = h;
          dout[73728 + LAYER * 32768 + n * 512 + hidb] = c;
        }
      }
    }

    // ---- boundary ----
    if (p < TT) {
      const int tgt = p + 1;
      WAITV(0);                                // h stores drained & MALL-visible
      __builtin_amdgcn_s_barrier();            // all waves of this WG done phase p
      if (tid == 0)
        __hip_atomic_store(slots + wg, tgt, __ATOMIC_RELAXED,
                           __HIP_MEMORY_SCOPE_AGENT);

      if constexpr (LAYER == 0) {
        // L0: fall through — acquire happens mid-body of phase tgt
      } else {
        // L1: only gen0 (h_a[tgt] ready); gen1 handled mid-phase
        if (wv == 0 && !broken) {
          unsigned spins = 0;
          while (__hip_atomic_load(gens + 0, __ATOMIC_RELAXED,
                                   __HIP_MEMORY_SCOPE_AGENT) < tgt) {
            __builtin_amdgcn_s_sleep(1);
            if (++spins > (1u << 20)) { broken = true; break; }
          }
        }
        __builtin_amdgcn_s_barrier();          // release all waves into next phase
      }
    }
  }
}

__global__ __launch_bounds__(256, 1) void k_lstm(const f16* __restrict__ xh,
                                                 const f16* __restrict__ wp,
                                                 f16* __restrict__ ha, f16* __restrict__ hb,
                                                 int* __restrict__ slots,
                                                 const float* __restrict__ c0,
                                                 const float* __restrict__ b0,
                                                 const float* __restrict__ b1,
                                                 float* __restrict__ dout) {
  extern __shared__ f16 lds[];
  if (blockIdx.x < 32) lstm_body<0>(xh, wp, ha, hb, slots, c0, b0, dout, lds);
  else                 lstm_body<1>(xh, wp, ha, hb, slots, c0, b1, dout, lds);
}

// ---------------- final FC ----------------

__global__ void k_fc(const float* __restrict__ hn1, const float* __restrict__ fcw,
                     const float* __restrict__ fcb, float* __restrict__ out) {
  int n = blockIdx.x, cc = threadIdx.x;   // 64 x 128
  const float* h = hn1 + n * 512;
  const float* wr = fcw + cc * 512;
  float s = fcb[cc];
#pragma unroll 4
  for (int k = 0; k < 512; k += 4) {
    float4 hv = *(const float4*)(h + k);
    float4 wv = *(const float4*)(wr + k);
    s += hv.x * wv.x + hv.y * wv.y + hv.z * wv.z + hv.w * wv.w;
  }
  out[n * 128 + cc] = s;
}

// ---------------- launch ----------------

extern "C" void kernel_launch(void* const* d_in, const int* in_sizes, int n_in,
                              void* d_out, int out_size, void* d_ws, size_t ws_size,
                              hipStream_t stream) {
  const float* x   = (const float*)d_in[0];
  const float* h0  = (const float*)d_in[1];
  const float* c0  = (const float*)d_in[2];
  const float* W0  = (const float*)d_in[3];
  const float* U0  = (const float*)d_in[4];
  const float* b0  = (const float*)d_in[5];
  const float* W1  = (const float*)d_in[6];
  const float* U1  = (const float*)d_in[7];
  const float* b1  = (const float*)d_in[8];
  const float* fcw = (const float*)d_in[9];
  const float* fcb = (const float*)d_in[10];
  float* out = (float*)d_out;
  char* ws = (char*)d_ws;
  if (ws_size < (size_t)WS_NEED) return;

  f16* xh = (f16*)(ws + XH_OFF);
  f16* wp = (f16*)(ws + WP_OFF);
  f16* ha = (f16*)(ws + HA_OFF);
  f16* hb = (f16*)(ws + HB_OFF);
  int* slots = (int*)(ws + BAR_OFF);

  (void)hipFuncSetAttribute((const void*)k_lstm,
                            hipFuncAttributeMaxDynamicSharedMemorySize, LDS_BYTES);

  k_pack_w<<<(458752 + 255) / 256, 256, 0, stream>>>(W0, U0, W1, U1, wp);
  k_pack_x<<<(1048576 + 255) / 256, 256, 0, stream>>>(x, xh);
  k_init<<<256, 256, 0, stream>>>(h0, ha, hb, slots);
  k_lstm<<<64, 256, LDS_BYTES, stream>>>(xh, wp, ha, hb, slots, c0, b0, b1, out);
  k_fc<<<64, 128, 0, stream>>>(out + 8192 + 32768, fcw, fcb, out);
}

// Round 20
// 3417.633 us; speedup vs baseline: 1.0761x; 1.0761x over previous
//
#include <hip/hip_runtime.h>
#include <hip/hip_fp16.h>

typedef _Float16 f16;
typedef _Float16 f16x8 __attribute__((ext_vector_type(8)));
typedef float f32x4 __attribute__((ext_vector_type(4)));

#define TT 512

// ws layout (bytes)
#define XH_OFF    0                 // x as f16: 512*64*256*2 = 16777216
#define WP_OFF    16777216          // packed weights f16: 7340032
#define HA_OFF    24117248          // h_a hub ring: 4 x 65536
#define HB_OFF    24379392          // h_b hub double buffer: 2 x 65536
#define BAR_OFF   24510464          // 64 slot ints + 2 gen ints
#define WS_NEED   24510976

#define WP_L1_HOFF 1572864          // half-offset of layer1 slice in wpack
#define LDS_BYTES 131072            // weights only

// counted vmcnt wait + scheduler fence (guide rule #18)
#define WAITV(N) do { \
    asm volatile("s_waitcnt vmcnt(" #N ")" ::: "memory"); \
    __builtin_amdgcn_sched_barrier(0); \
  } while (0)

// ---------------- prep kernels ----------------

__global__ void k_pack_w(const float* __restrict__ W0, const float* __restrict__ U0,
                         const float* __restrict__ W1, const float* __restrict__ U1,
                         f16* __restrict__ wp) {
  int idx = blockIdx.x * 256 + threadIdx.x;
  if (idx >= 458752) return;
  if (idx < 196608) {              // layer0: [w][ct][s=24][lane]
    int w = idx / 6144, r = idx % 6144;
    int ct = r / 1536, r2 = r % 1536;
    int s = r2 / 64, lane = r2 % 64;
    int g = ct * 512 + w * 16 + (lane & 15);
    int kb = s * 32 + (lane >> 4) * 8;
    f16* dst = wp + (size_t)idx * 8;
#pragma unroll
    for (int j = 0; j < 8; ++j) {
      int k = kb + j;
      float v = (k < 256) ? W0[g * 256 + k] : U0[g * 512 + (k - 256)];
      dst[j] = (f16)v;
    }
  } else {                         // layer1: [w][ct][s=32][lane]
    int i2 = idx - 196608;
    int w = i2 / 8192, r = i2 % 8192;
    int ct = r / 2048, r2 = r % 2048;
    int s = r2 / 64, lane = r2 % 64;
    int g = ct * 512 + w * 16 + (lane & 15);
    int kb = s * 32 + (lane >> 4) * 8;
    f16* dst = wp + (size_t)WP_L1_HOFF + (size_t)i2 * 8;
#pragma unroll
    for (int j = 0; j < 8; ++j) {
      int k = kb + j;
      float v = (k < 512) ? W1[g * 512 + k] : U1[g * 512 + (k - 512)];
      dst[j] = (f16)v;
    }
  }
}

__global__ void k_pack_x(const float* __restrict__ x, f16* __restrict__ xh) {
  int t = blockIdx.x * 256 + threadIdx.x;
  if (t >= 1048576) return;
  const float4* s = (const float4*)(x) + (size_t)t * 2;
  float4 a = s[0], b = s[1];
  f16x8 o;
  o[0] = (f16)a.x; o[1] = (f16)a.y; o[2] = (f16)a.z; o[3] = (f16)a.w;
  o[4] = (f16)b.x; o[5] = (f16)b.y; o[6] = (f16)b.z; o[7] = (f16)b.w;
  *(f16x8*)(xh + (size_t)t * 8) = o;
}

__global__ void k_init(const float* __restrict__ h0, f16* __restrict__ ha,
                       f16* __restrict__ hb, int* __restrict__ slots) {
  int i = blockIdx.x * 256 + threadIdx.x;
  if (i < 32768) {
    ha[i] = (f16)h0[i];                    // h_a ring[0] <- h0[0]
  } else if (i < 65536) {
    hb[i] = (f16)h0[i];                    // h_b buf1 <- h0[1]
  }
  if (i < 66) slots[i] = 0;                // 64 slots + 2 gen words
}

// ---------------- math helpers ----------------

__device__ __forceinline__ float sigmoidf_(float x) {
  return 1.0f / (1.0f + __expf(-x));
}
__device__ __forceinline__ float tanhf_(float x) {
  x = fminf(fmaxf(x, -15.0f), 15.0f);
  float e = __expf(-2.0f * x);
  return (1.0f - e) / (1.0f + e);
}

// device-coherent (MALL) 16B load: bypasses stale L1/L2 (validated path)
__device__ __forceinline__ uint4 ldg_coh(const void* base, unsigned voff) {
  uint4 d;
  asm volatile("global_load_dwordx4 %0, %1, %2 sc0 sc1"
               : "=v"(d) : "v"(voff), "s"(base) : "memory");
  return d;
}
// normal cached 16B load (read-only x)
__device__ __forceinline__ uint4 ldg_x(const void* base, unsigned voff) {
  uint4 d;
  asm volatile("global_load_dwordx4 %0, %1, %2"
               : "=v"(d) : "v"(voff), "s"(base) : "memory");
  return d;
}

// ---------------- persistent LSTM ----------------

template <int LAYER>
__device__ void lstm_body(const f16* __restrict__ xh, const f16* __restrict__ wp,
                          f16* __restrict__ ha, f16* __restrict__ hb,
                          int* __restrict__ slots, const float* __restrict__ c0,
                          const float* __restrict__ bb, float* __restrict__ dout,
                          f16* lds) {
  constexpr int NX = (LAYER == 0) ? 8 : 0;    // x K-steps (K=32 each)
  constexpr int NH = (LAYER == 0) ? 16 : 32;  // h K-steps
  constexpr int NK = NX + NH;                 // LDS B layout stride
  const int wg = blockIdx.x;
  const int w = wg & 31;
  const int tid = threadIdx.x, lane = tid & 63, wv = tid >> 6;
  int* gens = slots + 64;                     // gens[0]=layer0, gens[1]=layer1

  // copy this WG's weight slice into LDS (once; reused all phases)
  {
    const uint4* src = (const uint4*)(wp + (LAYER ? (size_t)WP_L1_HOFF + (size_t)w * 65536
                                                  : (size_t)w * 49152));
    uint4* dst = (uint4*)lds;
    const int n16 = LAYER ? 8192 : 6144;    // halfs/8
    for (int i = tid; i < n16; i += 256) dst[i] = src[i];
  }

  const int j15 = lane & 15;
  const int l4 = lane >> 4;
  const int hidb = w * 16 + j15;
  const float bi = bb[hidb], bf = bb[512 + hidb], bo = bb[1024 + hidb], bc = bb[1536 + hidb];

  float cr[4];
#pragma unroll
  for (int r = 0; r < 4; ++r) {
    int n = 16 * wv + l4 * 4 + r;
    cr[r] = c0[(size_t)LAYER * 32768 + n * 512 + hidb];
  }

  // per-lane byte offsets: each wave owns rows 16*wv .. 16*wv+15 (no redundancy)
  const int row = 16 * wv + j15;
  const unsigned hoffs = (unsigned)(row * 1024 + l4 * 16);
  const unsigned xoffs = (unsigned)(row * 512 + l4 * 16);

  uint4 ax[(LAYER == 0) ? 8 : 1];
  uint4 ah[NH];

  auto issue_x = [&](int pp) {
    if constexpr (LAYER == 0) {
      const char* xb = (const char*)xh + (size_t)pp * 32768;
#pragma unroll
      for (int s = 0; s < 8; ++s) ax[s] = ldg_x(xb, xoffs + s * 64);
    }
  };

  __syncthreads();                           // weights staged
  issue_x(0);

  bool broken = false;
  for (int p = 0; p <= TT; ++p) {
    const char* hard = (const char*)ha + (size_t)(p & 3) * 65536;   // ring slot
    const char* hbrd = (const char*)hb + (size_t)(p & 1) * 65536;
    f16* hwr = (LAYER == 0) ? (ha + ((p + 1) & 3) * 32768)
                            : (hb + (((p & 1) ^ 1) * 32768));
    const bool active = (LAYER == 0) ? (p < TT) : (p >= 1);

    if (active) {
      f32x4 acc[4];
#pragma unroll
      for (int ct = 0; ct < 4; ++ct) acc[ct] = (f32x4){0.f, 0.f, 0.f, 0.f};

      auto mstep = [&](uint4 Au, int sB) {
        f16x8 a = __builtin_bit_cast(f16x8, Au);
#pragma unroll
        for (int ct = 0; ct < 4; ++ct) {
          f16x8 b = *(const f16x8*)(lds + (((ct * NK + sB) * 64 + lane) * 8));
          acc[ct] = __builtin_amdgcn_mfma_f32_16x16x32_f16(a, b, acc[ct], 0, 0, 0);
        }
      };

      if constexpr (LAYER == 0) {
        // 16 h loads on top of 8 in-flight x loads
#pragma unroll
        for (int t = 0; t < 16; ++t) ah[t] = ldg_coh(hard, hoffs + t * 64);
        WAITV(16);                            // x batch done
#pragma unroll
        for (int s = 0; s < 8; ++s) mstep(ax[s], s);
        WAITV(8);                             // h batch 0 done
#pragma unroll
        for (int t = 0; t < 8; ++t) mstep(ah[t], 8 + t);
        WAITV(0);                             // h batch 1 done
#pragma unroll
        for (int t = 8; t < 16; ++t) mstep(ah[t], 8 + t);
      } else {
        // --- L1: h_a half first; gen1 handshake overlapped mid-phase ---
#pragma unroll
        for (int t = 0; t < 16; ++t) ah[t] = ldg_coh(hard, hoffs + t * 64);
        WAITV(8);                             // h_a[0..7]
#pragma unroll
        for (int t = 0; t < 8; ++t) mstep(ah[t], t);

        // mid-phase gen1 handshake: L1 slot stores landed during h_a compute
        if (wv == 0 && !broken) {
          if (w == 0) {                       // L1 group leader (wg 32)
            const int* gs = slots + 32;
            unsigned spins = 0;
            for (;;) {
              int v = __hip_atomic_load(gs + (lane & 31), __ATOMIC_RELAXED,
                                        __HIP_MEMORY_SCOPE_AGENT);
              if (__all((int)(v >= p))) break;
              __builtin_amdgcn_s_sleep(1);
              if (++spins > (1u << 20)) { broken = true; break; }
            }
            __hip_atomic_store(gens + 1, p, __ATOMIC_RELAXED,
                               __HIP_MEMORY_SCOPE_AGENT);
          } else {
            unsigned spins = 0;
            while (__hip_atomic_load(gens + 1, __ATOMIC_RELAXED,
                                     __HIP_MEMORY_SCOPE_AGENT) < p) {
              __builtin_amdgcn_s_sleep(1);
              if (++spins > (1u << 20)) { broken = true; break; }
            }
          }
        }
        __builtin_amdgcn_s_barrier();         // h_b[p] readable

#pragma unroll
        for (int t = 16; t < 32; ++t) ah[t] = ldg_coh(hbrd, hoffs + (t - 16) * 64);
        WAITV(16);                            // h_a[8..15] (hides h_b RTT)
#pragma unroll
        for (int t = 8; t < 16; ++t) mstep(ah[t], t);
        WAITV(8);                             // h_b[0..7]
#pragma unroll
        for (int t = 16; t < 24; ++t) mstep(ah[t], t);
        WAITV(0);                             // h_b[8..15]
#pragma unroll
        for (int t = 24; t < 32; ++t) mstep(ah[t], t);
      }

      // epilogue straight from registers: acc[ct][r] = gate ct, row 16wv+l4*4+r, hid j15
      const bool last = (p == (LAYER ? TT : TT - 1));
#pragma unroll
      for (int r = 0; r < 4; ++r) {
        int n = 16 * wv + l4 * 4 + r;
        float gi = acc[0][r] + bi;
        float gf = acc[1][r] + bf;
        float go = acc[2][r] + bo;
        float gc = acc[3][r] + bc;
        float ig = sigmoidf_(gi), fg = sigmoidf_(gf), og = sigmoidf_(go);
        float cg = tanhf_(gc);
        float c = fg * cr[r] + ig * cg;
        cr[r] = c;
        float h = og * tanhf_(c);
        // pack (even,odd) hid pair across lane pair; write-through coherent store
        unsigned short us = __builtin_bit_cast(unsigned short, (f16)h);
        unsigned other = __shfl_xor((unsigned)us, 1, 64);
        if (!(lane & 1)) {
          unsigned pack = (unsigned)us | (other << 16);
          __hip_atomic_store((unsigned*)(hwr + n * 512 + hidb), pack,
                             __ATOMIC_RELAXED, __HIP_MEMORY_SCOPE_AGENT);
        }
        if (last) {
          dout[8192 + LAYER * 32768 + n * 512 + hidb] = h;
          dout[73728 + LAYER * 32768 + n * 512 + hidb] = c;
        }
      }
    }

    // ---- boundary: drain, converge, slot store, acquire for next phase ----
    if (p < TT) {
      const int tgt = p + 1;
      WAITV(0);                                // h stores drained & MALL-visible
      __builtin_amdgcn_s_barrier();            // all waves of this WG done phase p
      if (tid == 0)
        __hip_atomic_store(slots + wg, tgt, __ATOMIC_RELAXED,
                           __HIP_MEMORY_SCOPE_AGENT);

      if constexpr (LAYER == 0) {
        // --- L0 boundary ---
        if (p + 1 < TT) issue_x(p + 1);        // x latency hides under the wait
        if (wv == 0 && !broken) {
          if (w == 0) {
            const int* gs = slots;
            unsigned spins = 0;
            for (;;) {
              int v = __hip_atomic_load(gs + (lane & 31), __ATOMIC_RELAXED,
                                        __HIP_MEMORY_SCOPE_AGENT);
              if (__all((int)(v >= tgt))) break;
              __builtin_amdgcn_s_sleep(1);
              if (++spins > (1u << 20)) { broken = true; break; }
            }
            __hip_atomic_store(gens + 0, tgt, __ATOMIC_RELAXED,
                               __HIP_MEMORY_SCOPE_AGENT);
            const int needO = p - 1;           // ring safety vs L1 reads
            if (needO > 0 && !broken) {
              unsigned s2 = 0;
              while (__hip_atomic_load(gens + 1, __ATOMIC_RELAXED,
                                       __HIP_MEMORY_SCOPE_AGENT) < needO) {
                __builtin_amdgcn_s_sleep(2);
                if (++s2 > (1u << 20)) { broken = true; break; }
              }
            }
          } else {
            const int need1 = p - 1;
            unsigned spins = 0;
            for (;;) {
              unsigned long long g = __hip_atomic_load((const unsigned long long*)gens,
                                                       __ATOMIC_RELAXED,
                                                       __HIP_MEMORY_SCOPE_AGENT);
              int g0 = (int)(unsigned)g, g1 = (int)(unsigned)(g >> 32);
              if (g0 >= tgt && g1 >= need1) break;
              __builtin_amdgcn_s_sleep(2);
              if (++spins > (1u << 20)) { broken = true; break; }
            }
          }
        }
      } else {
        // --- L1 boundary: only gen0 (h_a[tgt] ready); gen1 handled mid-phase ---
        if (wv == 0 && !broken) {
          unsigned spins = 0;
          while (__hip_atomic_load(gens + 0, __ATOMIC_RELAXED,
                                   __HIP_MEMORY_SCOPE_AGENT) < tgt) {
            __builtin_amdgcn_s_sleep(1);
            if (++spins > (1u << 20)) { broken = true; break; }
          }
        }
      }
      __builtin_amdgcn_s_barrier();            // release all waves into next phase
    }
  }
}

__global__ __launch_bounds__(256, 1) void k_lstm(const f16* __restrict__ xh,
                                                 const f16* __restrict__ wp,
                                                 f16* __restrict__ ha, f16* __restrict__ hb,
                                                 int* __restrict__ slots,
                                                 const float* __restrict__ c0,
                                                 const float* __restrict__ b0,
                                                 const float* __restrict__ b1,
                                                 float* __restrict__ dout) {
  extern __shared__ f16 lds[];
  if (blockIdx.x < 32) lstm_body<0>(xh, wp, ha, hb, slots, c0, b0, dout, lds);
  else                 lstm_body<1>(xh, wp, ha, hb, slots, c0, b1, dout, lds);
}

// ---------------- final FC ----------------

__global__ void k_fc(const float* __restrict__ hn1, const float* __restrict__ fcw,
                     const float* __restrict__ fcb, float* __restrict__ out) {
  int n = blockIdx.x, cc = threadIdx.x;   // 64 x 128
  const float* h = hn1 + n * 512;
  const float* wr = fcw + cc * 512;
  float s = fcb[cc];
#pragma unroll 4
  for (int k = 0; k < 512; k += 4) {
    float4 hv = *(const float4*)(h + k);
    float4 wv = *(const float4*)(wr + k);
    s += hv.x * wv.x + hv.y * wv.y + hv.z * wv.z + hv.w * wv.w;
  }
  out[n * 128 + cc] = s;
}

// ---------------- launch ----------------

extern "C" void kernel_launch(void* const* d_in, const int* in_sizes, int n_in,
                              void* d_out, int out_size, void* d_ws, size_t ws_size,
                              hipStream_t stream) {
  const float* x   = (const float*)d_in[0];
  const float* h0  = (const float*)d_in[1];
  const float* c0  = (const float*)d_in[2];
  const float* W0  = (const float*)d_in[3];
  const float* U0  = (const float*)d_in[4];
  const float* b0  = (const float*)d_in[5];
  const float* W1  = (const float*)d_in[6];
  const float* U1  = (const float*)d_in[7];
  const float* b1  = (const float*)d_in[8];
  const float* fcw = (const float*)d_in[9];
  const float* fcb = (const float*)d_in[10];
  float* out = (float*)d_out;
  char* ws = (char*)d_ws;
  if (ws_size < (size_t)WS_NEED) return;

  f16* xh = (f16*)(ws + XH_OFF);
  f16* wp = (f16*)(ws + WP_OFF);
  f16* ha = (f16*)(ws + HA_OFF);
  f16* hb = (f16*)(ws + HB_OFF);
  int* slots = (int*)(ws + BAR_OFF);

  (void)hipFuncSetAttribute((const void*)k_lstm,
                            hipFuncAttributeMaxDynamicSharedMemorySize, LDS_BYTES);

  k_pack_w<<<(458752 + 255) / 256, 256, 0, stream>>>(W0, U0, W1, U1, wp);
  k_pack_x<<<(1048576 + 255) / 256, 256, 0, stream>>>(x, xh);
  k_init<<<256, 256, 0, stream>>>(h0, ha, hb, slots);
  k_lstm<<<64, 256, LDS_BYTES, stream>>>(xh, wp, ha, hb, slots, c0, b0, b1, out);
  k_fc<<<64, 128, 0, stream>>>(out + 8192 + 32768, fcw, fcb, out);
}